// Round 3
// baseline (404.227 us; speedup 1.0000x reference)
//
#include <hip/hip_runtime.h>
#include <hip/hip_bf16.h>
#include <stdint.h>

typedef __attribute__((ext_vector_type(8))) short short8v;     // 8 x bf16 (MFMA A/B frag)
typedef __attribute__((ext_vector_type(4))) float float4v;     // MFMA C/D frag / vec loads
typedef __attribute__((ext_vector_type(4))) unsigned short ushort4v;
typedef __attribute__((ext_vector_type(4))) unsigned int uint4v;

#define FINF __builtin_huge_valf()
#define BB 64
#define NN 512
#define DD 256
#define TT_SKEW 576   // skew rows: t = r + (j>>3) in [0, 511+63] -> pad to 576

// ws layout (bytes):
//   [0,        16777216)  xnb bf16 [B][N][D]
//   [16777216, 33554432)  ynb bf16 [B][N][D]
//   [33554432, 71303168)  cost_skew bf16 [B][576][512]  (element (r,j) at t=r+(j>>3), col j)

static __device__ __forceinline__ unsigned short f2bf(float f) {
  union { float f; uint32_t u; } a; a.f = f;
  uint32_t r = a.u + 0x7fffu + ((a.u >> 16) & 1u);   // RNE
  return (unsigned short)(r >> 16);
}
static __device__ __forceinline__ float bf2f(uint16_t v) {
  return __uint_as_float(((uint32_t)v) << 16);
}

// ---------------- Kernel 1: row-normalize + cast to bf16 ----------------
__global__ __launch_bounds__(256) void norm_cast_kernel(
    const float* __restrict__ x, const float* __restrict__ y,
    uint16_t* __restrict__ xnb, uint16_t* __restrict__ ynb)
{
  const int wave = threadIdx.x >> 6, lane = threadIdx.x & 63;
  const int row = blockIdx.x * 4 + wave;
  const float* src; uint16_t* dst;
  if (row < BB * NN) { src = x + (size_t)row * DD;            dst = xnb + (size_t)row * DD; }
  else               { src = y + (size_t)(row - BB*NN) * DD;  dst = ynb + (size_t)(row - BB*NN) * DD; }
  const float4v v = *(const float4v*)(src + lane * 4);
  float s = v[0]*v[0] + v[1]*v[1] + v[2]*v[2] + v[3]*v[3];
  #pragma unroll
  for (int d = 1; d < 64; d <<= 1) s += __shfl_xor(s, d, 64);
  const float inv = 1.0f / fmaxf(sqrtf(s), 1e-8f);
  ushort4v o;
  o[0] = f2bf(v[0] * inv); o[1] = f2bf(v[1] * inv);
  o[2] = f2bf(v[2] * inv); o[3] = f2bf(v[3] * inv);
  *(ushort4v*)(dst + lane * 4) = o;
}

// ---------------- Kernel 2: cost = 1 - xn·yn -> bf16 skewed layout ----------------
// 128x128 tile per block, 4 waves (2x2), BK=32, K=256. NT-GEMM, bf16 MFMA 16x16x32.
__global__ __launch_bounds__(256) void gemm_cost_kernel(
    const uint16_t* __restrict__ xnb, const uint16_t* __restrict__ ynb,
    uint16_t* __restrict__ skew)
{
  __shared__ uint16_t As[128 * 32];
  __shared__ uint16_t Bs[128 * 32];
  const int bid = blockIdx.x;
  const int b = bid >> 4, tm = (bid >> 2) & 3, tn = bid & 3;
  const int tid = threadIdx.x, wave = tid >> 6, lane = tid & 63;
  const int wr = wave >> 1, wc = wave & 1;

  const char* Ab = (const char*)(xnb + (size_t)b * NN * DD + (size_t)tm * 128 * DD);
  const char* Bb = (const char*)(ynb + (size_t)b * NN * DD + (size_t)tn * 128 * DD);

  float4v acc[4][4];
  #pragma unroll
  for (int i = 0; i < 4; i++)
    #pragma unroll
    for (int j = 0; j < 4; j++) acc[i][j] = (float4v){0.f, 0.f, 0.f, 0.f};

  const int seg0 = wave * 2;
  const int o0 = seg0 * 1024 + lane * 16;
  const int o1 = o0 + 1024;
  const int r0 = o0 >> 6, c0 = o0 & 63;
  const int r1 = o1 >> 6, c1 = o1 & 63;

  for (int kk = 0; kk < 8; kk++) {
    const int kb = kk * 64;
    __builtin_amdgcn_global_load_lds(
        (const __attribute__((address_space(1))) uint32_t*)(Ab + (size_t)r0 * 512 + kb + c0),
        (__attribute__((address_space(3))) uint32_t*)((char*)As + seg0 * 1024), 16, 0, 0);
    __builtin_amdgcn_global_load_lds(
        (const __attribute__((address_space(1))) uint32_t*)(Ab + (size_t)r1 * 512 + kb + c1),
        (__attribute__((address_space(3))) uint32_t*)((char*)As + (seg0 + 1) * 1024), 16, 0, 0);
    __builtin_amdgcn_global_load_lds(
        (const __attribute__((address_space(1))) uint32_t*)(Bb + (size_t)r0 * 512 + kb + c0),
        (__attribute__((address_space(3))) uint32_t*)((char*)Bs + seg0 * 1024), 16, 0, 0);
    __builtin_amdgcn_global_load_lds(
        (const __attribute__((address_space(1))) uint32_t*)(Bb + (size_t)r1 * 512 + kb + c1),
        (__attribute__((address_space(3))) uint32_t*)((char*)Bs + (seg0 + 1) * 1024), 16, 0, 0);
    __syncthreads();

    short8v af[4], bfr[4];
    #pragma unroll
    for (int mi = 0; mi < 4; mi++) {
      const int rr = wr * 64 + mi * 16 + (lane & 15);
      af[mi] = *(const short8v*)((const char*)As + rr * 64 + (lane >> 4) * 16);
    }
    #pragma unroll
    for (int nj = 0; nj < 4; nj++) {
      const int rr = wc * 64 + nj * 16 + (lane & 15);
      bfr[nj] = *(const short8v*)((const char*)Bs + rr * 64 + (lane >> 4) * 16);
    }
    #pragma unroll
    for (int mi = 0; mi < 4; mi++)
      #pragma unroll
      for (int nj = 0; nj < 4; nj++)
        acc[mi][nj] = __builtin_amdgcn_mfma_f32_16x16x32_bf16(af[mi], bfr[nj], acc[mi][nj], 0, 0, 0);
    __syncthreads();
  }

  uint16_t* Cb = skew + (size_t)b * TT_SKEW * NN;
  #pragma unroll
  for (int mi = 0; mi < 4; mi++)
    #pragma unroll
    for (int nj = 0; nj < 4; nj++) {
      const int cc = tn * 128 + wc * 64 + nj * 16 + (lane & 15);
      const int lg = cc >> 3;
      #pragma unroll
      for (int v = 0; v < 4; v++) {
        const int rr = tm * 128 + wr * 64 + mi * 16 + (lane >> 4) * 4 + v;
        Cb[(size_t)(rr + lg) * NN + cc] = f2bf(1.0f - acc[mi][nj][v]);
      }
    }
}

// ---------------- Kernel 3: DTW forward + backtrack + logsumexps ----------------
// One 64-lane wave per batch, launch_bounds(64,1) so the allocator can keep the
// depth-8 prefetch + state in VGPRs (R2's 48-VGPR cap spilled them to scratch).
// Lane l owns cols [8l,8l+8); lane l processes row r at step t=r+l.
// Post-shuffle critical path = 1 fmin + 1 add (prefix-min PW precomputed).
__global__ __launch_bounds__(64, 1) void dtw_kernel(
    const uint16_t* __restrict__ skew, float* __restrict__ out)
{
  extern __shared__ char lds_raw[];
  uint16_t* dec  = (uint16_t*)lds_raw;              // [256][64] u32 = 64 KB (2 rows/u32)
  uint16_t* rlo  = (uint16_t*)(lds_raw + 65536);    // [512]
  uint16_t* rhi  = (uint16_t*)(lds_raw + 66560);    // [512]
  float*  colpos = (float*)  (lds_raw + 67584);     // [512]

  const int l = threadIdx.x;
  const int b = blockIdx.x;
  const uint16_t* csk = skew + (size_t)b * TT_SKEW * NN;
  const uint16_t* cskl = csk + l * 8;

  float tprev[8], colsum[8];
  uint4v buf[8];
  #pragma unroll
  for (int c = 0; c < 8; c++) { tprev[c] = FINF; colsum[c] = 0.0f; }
  float cur_last = FINF;
  float sh_p_carry = FINF;   // previous step's sh_c == tc[r-1][8l-1]

  // prologue: depth-8 prefetch of steps 0..7 (1KB/wave each, contiguous)
  #pragma unroll
  for (int u = 0; u < 8; u++)
    buf[u] = *(const uint4v*)(cskl + (size_t)u * NN);

  for (int t = 0; t < TT_SKEW; t += 8) {
    #pragma unroll
    for (int u = 0; u < 8; u++) {
      const int tt = t + u;
      float sh_c = __shfl_up(cur_last, 1, 64);   // tc[r][8l-1] from lane l-1
      float sh_p = sh_p_carry;                   // tc[r-1][8l-1]
      if (l == 0) { sh_p = FINF; sh_c = (tt == 0) ? 0.0f : FINF; }
      sh_p_carry = sh_c;
      const int r = tt - l;
      if (r >= 0 && r < NN) {
        float cst[8], S[8];
        #pragma unroll
        for (int k = 0; k < 4; k++) {
          const uint32_t wv = buf[u][k];
          cst[2*k]   = __uint_as_float(wv << 16);
          cst[2*k+1] = __uint_as_float(wv & 0xFFFF0000u);
        }
        S[0] = cst[0];
        #pragma unroll
        for (int c = 1; c < 8; c++) S[c] = S[c-1] + cst[c];
        // dcp[c] = diag neighbor tc[r-1][col-1]; up[c] = tprev[c]
        float dcp[8];
        dcp[0] = sh_p;
        #pragma unroll
        for (int c = 1; c < 8; c++) dcp[c] = tprev[c-1];
        float mu[8], w8[8], PW[8];
        #pragma unroll
        for (int c = 0; c < 8; c++) mu[c] = fminf(dcp[c], tprev[c]);
        w8[0] = mu[0];
        #pragma unroll
        for (int c = 1; c < 8; c++) w8[c] = mu[c] - S[c-1];
        PW[0] = w8[0];
        #pragma unroll
        for (int c = 1; c < 8; c++) PW[c] = fminf(PW[c-1], w8[c]);
        // post-shuffle: tn[c] = min(PW[c], sh_c) + S[c]   (== sequential uu-chain)
        float tn[8];
        #pragma unroll
        for (int c = 0; c < 8; c++) tn[c] = fminf(PW[c], sh_c) + S[c];
        float lc[8];
        lc[0] = sh_c;
        #pragma unroll
        for (int c = 1; c < 8; c++) lc[c] = tn[c-1];
        uint32_t word = 0;
        #pragma unroll
        for (int c = 0; c < 8; c++) {
          // argmin with reference tie-break diag > up > left (exact comparisons)
          const bool e0 = (dcp[c] <= tprev[c]) && (dcp[c] <= lc[c]);
          const uint32_t dd = e0 ? 0u : ((tprev[c] <= lc[c]) ? 1u : 2u);
          word |= dd << (2 * c);
          colsum[c] += cst[c];
        }
        dec[(r >> 1) * 128 + 2 * l + (r & 1)] = (uint16_t)word;
        #pragma unroll
        for (int c = 0; c < 8; c++) tprev[c] = tn[c];
        cur_last = tn[7];
      }
      const int tnx = tt + 8;
      if (tnx < TT_SKEW)
        buf[u] = *(const uint4v*)(cskl + (size_t)tnx * NN);
    }
  }

  // ---- neg = logsumexp over column sums ----
  float mx = colsum[0];
  #pragma unroll
  for (int c = 1; c < 8; c++) mx = fmaxf(mx, colsum[c]);
  #pragma unroll
  for (int d = 1; d < 64; d <<= 1) mx = fmaxf(mx, __shfl_xor(mx, d, 64));
  float se = 0.f;
  #pragma unroll
  for (int c = 0; c < 8; c++) se += expf(colsum[c] - mx);
  #pragma unroll
  for (int d = 1; d < 64; d <<= 1) se += __shfl_xor(se, d, 64);
  const float neg = mx + logf(se);

  // ---- backtrack: per-row contiguous column interval of the path ----
  for (int r = l; r < NN; r += 64) { rlo[r] = 1; rhi[r] = 0; colpos[r] = 0.0f; }
  __syncthreads();
  if (l == 0) {
    int i = NN - 1, j = NN - 1, hicur = NN - 1;
    const uint32_t* dec32 = (const uint32_t*)dec;
    int cidx = -1; uint32_t cw = 0;
    while (i > 0 && j > 0) {
      const int widx = (i >> 1) * 64 + (j >> 3);
      if (widx != cidx) { cw = dec32[widx]; cidx = widx; }
      const uint32_t dd = (cw >> (((i & 1) << 4) + ((j & 7) << 1))) & 3u;
      if (dd == 2u) { j--; }           // left: stay in row
      else {
        rlo[i] = (uint16_t)j; rhi[i] = (uint16_t)hicur;  // leave row i
        i--;
        if (dd == 0u) j--;             // diag also moves left
        hicur = j;                     // entry column of new row
      }
    }
    rlo[i] = (uint16_t)j; rhi[i] = (uint16_t)hicur;      // pending row at exit
  }
  __syncthreads();
  // colpos[m] = sum_n cost*path (rows parallel across lanes; skew-layout reads)
  for (int r = l; r < NN; r += 64) {
    const int lo = rlo[r], hi = rhi[r];
    for (int j = lo; j <= hi; j++) {
      const float cv = bf2f(csk[(size_t)(r + (j >> 3)) * NN + j]);
      atomicAdd(&colpos[j], cv);
    }
  }
  // reference always sets p[0,0]=1
  if (l == 0 && rlo[0] != 0) atomicAdd(&colpos[0], bf2f(csk[0]));
  __syncthreads();

  // ---- pos = logsumexp over colpos ----
  float mv[8];
  float mx2 = -FINF;
  #pragma unroll
  for (int k = 0; k < 8; k++) { mv[k] = colpos[l + 64 * k]; mx2 = fmaxf(mx2, mv[k]); }
  #pragma unroll
  for (int d = 1; d < 64; d <<= 1) mx2 = fmaxf(mx2, __shfl_xor(mx2, d, 64));
  float se2 = 0.f;
  #pragma unroll
  for (int k = 0; k < 8; k++) se2 += expf(mv[k] - mx2);
  #pragma unroll
  for (int d = 1; d < 64; d <<= 1) se2 += __shfl_xor(se2, d, 64);
  const float pos = mx2 + logf(se2);

  if (l == 0) out[b] = pos - neg;
}

extern "C" void kernel_launch(void* const* d_in, const int* in_sizes, int n_in,
                              void* d_out, int out_size, void* d_ws, size_t ws_size,
                              hipStream_t stream)
{
  (void)in_sizes; (void)n_in; (void)out_size; (void)ws_size;
  const float* x = (const float*)d_in[0];
  const float* y = (const float*)d_in[1];
  float* out = (float*)d_out;
  char* ws = (char*)d_ws;
  uint16_t* xnb  = (uint16_t*)ws;
  uint16_t* ynb  = (uint16_t*)(ws + (size_t)16777216);
  uint16_t* skew = (uint16_t*)(ws + (size_t)33554432);

  (void)hipFuncSetAttribute((const void*)dtw_kernel,
                            hipFuncAttributeMaxDynamicSharedMemorySize, 69632);

  norm_cast_kernel<<<16384, 256, 0, stream>>>(x, y, xnb, ynb);
  gemm_cost_kernel<<<1024, 256, 0, stream>>>(xnb, ynb, skew);
  dtw_kernel<<<64, 64, 69632, stream>>>(skew, out);
}

// Round 4
// 346.653 us; speedup vs baseline: 1.1661x; 1.1661x over previous
//
#include <hip/hip_runtime.h>
#include <hip/hip_bf16.h>
#include <stdint.h>

typedef __attribute__((ext_vector_type(8))) short short8v;     // 8 x bf16 (MFMA A/B frag)
typedef __attribute__((ext_vector_type(4))) float float4v;     // MFMA C/D frag / vec loads
typedef __attribute__((ext_vector_type(4))) unsigned short ushort4v;
typedef __attribute__((ext_vector_type(4))) unsigned int uint4v;

#define FINF __builtin_huge_valf()
#define BB 64
#define NN 512
#define DD 256
#define TT_SKEW 576   // skew rows: t = r + (j>>3) in [0, 511+63] -> pad to 576

// ws layout (bytes):
//   [0,        16777216)  xnb bf16 [B][N][D]
//   [16777216, 33554432)  ynb bf16 [B][N][D]
//   [33554432, 71303168)  cost_skew bf16 [B][576][512]  (cell (r,j) at row t=r+(j>>3), col j)
//   [71303168, 71303424)  negbuf f32 [64]

static __device__ __forceinline__ unsigned short f2bf(float f) {
  union { float f; uint32_t u; } a; a.f = f;
  uint32_t r = a.u + 0x7fffu + ((a.u >> 16) & 1u);   // RNE
  return (unsigned short)(r >> 16);
}
static __device__ __forceinline__ float bf2f(uint16_t v) {
  return __uint_as_float(((uint32_t)v) << 16);
}

// ---------------- Kernel 0: zero the skew-layout pad cells ----------------
// Row t<64: cols [8(t+1), 512) are pad; row t in [512,576): cols [0, 8(t-511)).
__global__ __launch_bounds__(64) void pad_zero_kernel(uint16_t* __restrict__ skew)
{
  const int bid = blockIdx.x;
  const int b = bid >> 7, k = bid & 127;
  const int t   = (k < 64) ? k : (448 + k);          // 0..63 or 512..575
  const int jlo = (k < 64) ? 8 * (t + 1) : 0;
  const int jhi = (k < 64) ? 512 : 8 * (t - 511);
  uint16_t* p = skew + ((size_t)b * TT_SKEW + t) * NN;
  const int j = jlo + (int)threadIdx.x * 8;
  if (j < jhi) *(uint4v*)(p + j) = (uint4v){0u, 0u, 0u, 0u};
}

// ---------------- Kernel 1: row-normalize + cast to bf16 ----------------
__global__ __launch_bounds__(256) void norm_cast_kernel(
    const float* __restrict__ x, const float* __restrict__ y,
    uint16_t* __restrict__ xnb, uint16_t* __restrict__ ynb)
{
  const int wave = threadIdx.x >> 6, lane = threadIdx.x & 63;
  const int row = blockIdx.x * 4 + wave;
  const float* src; uint16_t* dst;
  if (row < BB * NN) { src = x + (size_t)row * DD;            dst = xnb + (size_t)row * DD; }
  else               { src = y + (size_t)(row - BB*NN) * DD;  dst = ynb + (size_t)(row - BB*NN) * DD; }
  const float4v v = *(const float4v*)(src + lane * 4);
  float s = v[0]*v[0] + v[1]*v[1] + v[2]*v[2] + v[3]*v[3];
  #pragma unroll
  for (int d = 1; d < 64; d <<= 1) s += __shfl_xor(s, d, 64);
  const float inv = 1.0f / fmaxf(sqrtf(s), 1e-8f);
  ushort4v o;
  o[0] = f2bf(v[0] * inv); o[1] = f2bf(v[1] * inv);
  o[2] = f2bf(v[2] * inv); o[3] = f2bf(v[3] * inv);
  *(ushort4v*)(dst + lane * 4) = o;
}

// ---------------- Kernel 2: cost = 1 - xn·yn -> bf16 skewed layout ----------------
__global__ __launch_bounds__(256) void gemm_cost_kernel(
    const uint16_t* __restrict__ xnb, const uint16_t* __restrict__ ynb,
    uint16_t* __restrict__ skew)
{
  __shared__ uint16_t As[128 * 32];
  __shared__ uint16_t Bs[128 * 32];
  const int bid = blockIdx.x;
  const int b = bid >> 4, tm = (bid >> 2) & 3, tn = bid & 3;
  const int tid = threadIdx.x, wave = tid >> 6, lane = tid & 63;
  const int wr = wave >> 1, wc = wave & 1;

  const char* Ab = (const char*)(xnb + (size_t)b * NN * DD + (size_t)tm * 128 * DD);
  const char* Bb = (const char*)(ynb + (size_t)b * NN * DD + (size_t)tn * 128 * DD);

  float4v acc[4][4];
  #pragma unroll
  for (int i = 0; i < 4; i++)
    #pragma unroll
    for (int j = 0; j < 4; j++) acc[i][j] = (float4v){0.f, 0.f, 0.f, 0.f};

  const int seg0 = wave * 2;
  const int o0 = seg0 * 1024 + lane * 16;
  const int o1 = o0 + 1024;
  const int r0 = o0 >> 6, c0 = o0 & 63;
  const int r1 = o1 >> 6, c1 = o1 & 63;

  for (int kk = 0; kk < 8; kk++) {
    const int kb = kk * 64;
    __builtin_amdgcn_global_load_lds(
        (const __attribute__((address_space(1))) uint32_t*)(Ab + (size_t)r0 * 512 + kb + c0),
        (__attribute__((address_space(3))) uint32_t*)((char*)As + seg0 * 1024), 16, 0, 0);
    __builtin_amdgcn_global_load_lds(
        (const __attribute__((address_space(1))) uint32_t*)(Ab + (size_t)r1 * 512 + kb + c1),
        (__attribute__((address_space(3))) uint32_t*)((char*)As + (seg0 + 1) * 1024), 16, 0, 0);
    __builtin_amdgcn_global_load_lds(
        (const __attribute__((address_space(1))) uint32_t*)(Bb + (size_t)r0 * 512 + kb + c0),
        (__attribute__((address_space(3))) uint32_t*)((char*)Bs + seg0 * 1024), 16, 0, 0);
    __builtin_amdgcn_global_load_lds(
        (const __attribute__((address_space(1))) uint32_t*)(Bb + (size_t)r1 * 512 + kb + c1),
        (__attribute__((address_space(3))) uint32_t*)((char*)Bs + (seg0 + 1) * 1024), 16, 0, 0);
    __syncthreads();

    short8v af[4], bfr[4];
    #pragma unroll
    for (int mi = 0; mi < 4; mi++) {
      const int rr = wr * 64 + mi * 16 + (lane & 15);
      af[mi] = *(const short8v*)((const char*)As + rr * 64 + (lane >> 4) * 16);
    }
    #pragma unroll
    for (int nj = 0; nj < 4; nj++) {
      const int rr = wc * 64 + nj * 16 + (lane & 15);
      bfr[nj] = *(const short8v*)((const char*)Bs + rr * 64 + (lane >> 4) * 16);
    }
    #pragma unroll
    for (int mi = 0; mi < 4; mi++)
      #pragma unroll
      for (int nj = 0; nj < 4; nj++)
        acc[mi][nj] = __builtin_amdgcn_mfma_f32_16x16x32_bf16(af[mi], bfr[nj], acc[mi][nj], 0, 0, 0);
    __syncthreads();
  }

  uint16_t* Cb = skew + (size_t)b * TT_SKEW * NN;
  #pragma unroll
  for (int mi = 0; mi < 4; mi++)
    #pragma unroll
    for (int nj = 0; nj < 4; nj++) {
      const int cc = tn * 128 + wc * 64 + nj * 16 + (lane & 15);
      const int lg = cc >> 3;
      #pragma unroll
      for (int v = 0; v < 4; v++) {
        const int rr = tm * 128 + wr * 64 + mi * 16 + (lane >> 4) * 4 + v;
        Cb[(size_t)(rr + lg) * NN + cc] = f2bf(1.0f - acc[mi][nj][v]);
      }
    }
}

// ---------------- Kernel 3: neg[b] = LSE over column sums ----------------
// Column sums of cost == column sums of skew (pads zeroed). 256 thr, 2 cols each.
__global__ __launch_bounds__(256) void neg_lse_kernel(
    const uint16_t* __restrict__ skew, float* __restrict__ negbuf)
{
  __shared__ float sm[8];
  const int b = blockIdx.x, tid = threadIdx.x;
  const int wave = tid >> 6, lane = tid & 63;
  const uint32_t* p = (const uint32_t*)(skew + (size_t)b * TT_SKEW * NN) + tid;
  float s0 = 0.f, s1 = 0.f;
  #pragma unroll 8
  for (int t = 0; t < TT_SKEW; ++t) {
    const uint32_t w = p[t * 256];
    s0 += __uint_as_float(w << 16);
    s1 += __uint_as_float(w & 0xFFFF0000u);
  }
  float m = fmaxf(s0, s1);
  #pragma unroll
  for (int d = 1; d < 64; d <<= 1) m = fmaxf(m, __shfl_xor(m, d, 64));
  if (lane == 0) sm[wave] = m;
  __syncthreads();
  m = fmaxf(fmaxf(sm[0], sm[1]), fmaxf(sm[2], sm[3]));
  float e = expf(s0 - m) + expf(s1 - m);
  #pragma unroll
  for (int d = 1; d < 64; d <<= 1) e += __shfl_xor(e, d, 64);
  if (lane == 0) sm[4 + wave] = e;
  __syncthreads();
  if (tid == 0) negbuf[b] = m + logf(sm[4] + sm[5] + sm[6] + sm[7]);
}

// ---------------- Kernel 4: DTW forward + backtrack + pos LSE ----------------
// One 64-lane wave per batch. Lane l owns cols [8l,8l+8); processes row r=t-l.
// Cost rows staged via global_load_lds into a 16-slot LDS ring; counted
// s_waitcnt vmcnt(6) keeps ~9 rows in flight (structural pipeline the
// compiler can't sink/spill away). Branchless inner loop; state cndmask'd.
// LDS: [0,16K) ring | [16K,80K) dec u64[128][64] | rlo | rhi | colpos | dump
__global__ __launch_bounds__(64, 1) void dtw_kernel(
    const uint16_t* __restrict__ skew, const float* __restrict__ negbuf,
    float* __restrict__ out)
{
  extern __shared__ char lds_raw[];
  const int l = threadIdx.x;
  const int b = blockIdx.x;
  const uint16_t* csk = skew + (size_t)b * TT_SKEW * NN;
  const char* gsrc = (const char*)csk + 16 * l;     // per-lane global src base

  // prologue: stage rows 0..15 into ring slots 0..15
  #pragma unroll
  for (int i = 0; i < 16; ++i) {
    __builtin_amdgcn_global_load_lds(
        (const __attribute__((address_space(1))) uint32_t*)(gsrc + i * 1024),
        (__attribute__((address_space(3))) uint32_t*)(lds_raw + i * 1024), 16, 0, 0);
  }

  float tprev[8];
  #pragma unroll
  for (int c = 0; c < 8; ++c) tprev[c] = FINF;
  float sh_p_carry = FINF, cur_last = FINF;

  asm volatile("s_waitcnt vmcnt(6)" ::: "memory");
  __builtin_amdgcn_sched_barrier(0);
  uint4v cur = *(const uint4v*)(lds_raw + 16 * l);   // row 0

  for (int tt = 0; tt < TT_SKEW; ++tt) {
    asm volatile("s_waitcnt vmcnt(6)" ::: "memory");  // rows <= tt+9 landed
    __builtin_amdgcn_sched_barrier(0);
    const int tn1 = (tt + 1 < TT_SKEW) ? tt + 1 : TT_SKEW - 1;
    const uint4v nxt = *(const uint4v*)(lds_raw + (tn1 & 15) * 1024 + 16 * l);

    float sh_c = __shfl_up(cur_last, 1, 64);   // tc[r][8l-1] from lane l-1
    float sh_p = sh_p_carry;                   // tc[r-1][8l-1]
    if (l == 0) { sh_p = FINF; sh_c = (tt == 0) ? 0.0f : FINF; }
    sh_p_carry = sh_c;
    const int r = tt - l;
    const bool valid = (r >= 0) && (r < NN);

    // unpack + cost prefix sums
    float S[8];
    {
      float c0 = __uint_as_float(cur[0] << 16);
      float c1 = __uint_as_float(cur[0] & 0xFFFF0000u);
      float c2 = __uint_as_float(cur[1] << 16);
      float c3 = __uint_as_float(cur[1] & 0xFFFF0000u);
      float c4 = __uint_as_float(cur[2] << 16);
      float c5 = __uint_as_float(cur[2] & 0xFFFF0000u);
      float c6 = __uint_as_float(cur[3] << 16);
      float c7 = __uint_as_float(cur[3] & 0xFFFF0000u);
      S[0] = c0; S[1] = S[0] + c1; S[2] = S[1] + c2; S[3] = S[2] + c3;
      S[4] = S[3] + c4; S[5] = S[4] + c5; S[6] = S[5] + c6; S[7] = S[6] + c7;
    }
    float dcp[8];
    dcp[0] = sh_p;
    #pragma unroll
    for (int c = 1; c < 8; ++c) dcp[c] = tprev[c - 1];
    float w8[8], PW[8];
    w8[0] = fminf(dcp[0], tprev[0]);
    #pragma unroll
    for (int c = 1; c < 8; ++c) w8[c] = fminf(dcp[c], tprev[c]) - S[c - 1];
    PW[0] = w8[0];
    #pragma unroll
    for (int c = 1; c < 8; ++c) PW[c] = fminf(PW[c - 1], w8[c]);
    float tnv[8];
    #pragma unroll
    for (int c = 0; c < 8; ++c) tnv[c] = fminf(PW[c], sh_c) + S[c];
    float lc[8];
    lc[0] = sh_c;
    #pragma unroll
    for (int c = 1; c < 8; ++c) lc[c] = tnv[c - 1];
    uint32_t word = 0;
    #pragma unroll
    for (int c = 0; c < 8; ++c) {
      // tie-break diag > up > left, exact neighbor comparisons
      const bool diag = dcp[c] <= fminf(tprev[c], lc[c]);
      const uint32_t dd = diag ? 0u : ((tprev[c] <= lc[c]) ? 1u : 2u);
      word |= dd << (2 * c);
    }
    const int rc = r & 511;
    const int a_ok  = 16384 + ((rc >> 2) << 9) + (l << 3) + ((rc & 3) << 1);
    const int a_dmp = 86016 + (l << 1);
    *(uint16_t*)(lds_raw + (valid ? a_ok : a_dmp)) = (uint16_t)word;
    #pragma unroll
    for (int c = 0; c < 8; ++c) tprev[c] = valid ? tnv[c] : tprev[c];
    cur_last = tprev[7];

    if (tt + 16 < TT_SKEW) {
      __builtin_amdgcn_global_load_lds(
          (const __attribute__((address_space(1))) uint32_t*)(gsrc + (tt + 16) * 1024),
          (__attribute__((address_space(3))) uint32_t*)(lds_raw + ((tt + 16) & 15) * 1024),
          16, 0, 0);
    }
    cur = nxt;
  }

  uint16_t* rlo   = (uint16_t*)(lds_raw + 81920);
  uint16_t* rhi   = (uint16_t*)(lds_raw + 82944);
  float*    colpos = (float*) (lds_raw + 83968);
  const uint64_t* dec64 = (const uint64_t*)(lds_raw + 16384);

  // ---- backtrack: per-row contiguous column interval of the path ----
  for (int r = l; r < NN; r += 64) { rlo[r] = 1; rhi[r] = 0; colpos[r] = 0.0f; }
  __syncthreads();
  if (l == 0) {
    int i = NN - 1, j = NN - 1, hicur = NN - 1;
    int cidx = -1; uint64_t cw = 0;
    while (i > 0 && j > 0) {
      const int widx = (i >> 2) * 64 + (j >> 3);
      if (widx != cidx) { cw = dec64[widx]; cidx = widx; }
      const uint32_t dd = (uint32_t)(cw >> (((i & 3) << 4) + ((j & 7) << 1))) & 3u;
      if (dd == 2u) { j--; }           // left: stay in row
      else {
        rlo[i] = (uint16_t)j; rhi[i] = (uint16_t)hicur;  // leave row i
        i--;
        if (dd == 0u) j--;             // diag also moves left
        hicur = j;                     // entry column of new row
      }
    }
    rlo[i] = (uint16_t)j; rhi[i] = (uint16_t)hicur;      // pending row at exit
  }
  __syncthreads();
  // colpos[m] = sum_n cost*path (rows parallel across lanes; skew-layout reads)
  for (int r = l; r < NN; r += 64) {
    const int lo = rlo[r], hi = rhi[r];
    for (int j = lo; j <= hi; j++) {
      const float cv = bf2f(csk[(size_t)(r + (j >> 3)) * NN + j]);
      atomicAdd(&colpos[j], cv);
    }
  }
  // reference always sets p[0,0]=1
  if (l == 0 && rlo[0] != 0) atomicAdd(&colpos[0], bf2f(csk[0]));
  __syncthreads();

  // ---- pos = logsumexp over colpos ----
  float mv[8];
  float mx2 = -FINF;
  #pragma unroll
  for (int k = 0; k < 8; k++) { mv[k] = colpos[l + 64 * k]; mx2 = fmaxf(mx2, mv[k]); }
  #pragma unroll
  for (int d = 1; d < 64; d <<= 1) mx2 = fmaxf(mx2, __shfl_xor(mx2, d, 64));
  float se2 = 0.f;
  #pragma unroll
  for (int k = 0; k < 8; k++) se2 += expf(mv[k] - mx2);
  #pragma unroll
  for (int d = 1; d < 64; d <<= 1) se2 += __shfl_xor(se2, d, 64);
  const float pos = mx2 + logf(se2);

  if (l == 0) out[b] = pos - negbuf[b];
}

extern "C" void kernel_launch(void* const* d_in, const int* in_sizes, int n_in,
                              void* d_out, int out_size, void* d_ws, size_t ws_size,
                              hipStream_t stream)
{
  (void)in_sizes; (void)n_in; (void)out_size; (void)ws_size;
  const float* x = (const float*)d_in[0];
  const float* y = (const float*)d_in[1];
  float* out = (float*)d_out;
  char* ws = (char*)d_ws;
  uint16_t* xnb  = (uint16_t*)ws;
  uint16_t* ynb  = (uint16_t*)(ws + (size_t)16777216);
  uint16_t* skew = (uint16_t*)(ws + (size_t)33554432);
  float*  negbuf = (float*)  (ws + (size_t)71303168);

  (void)hipFuncSetAttribute((const void*)dtw_kernel,
                            hipFuncAttributeMaxDynamicSharedMemorySize, 90112);

  pad_zero_kernel<<<8192, 64, 0, stream>>>(skew);
  norm_cast_kernel<<<16384, 256, 0, stream>>>(x, y, xnb, ynb);
  gemm_cost_kernel<<<1024, 256, 0, stream>>>(xnb, ynb, skew);
  neg_lse_kernel<<<64, 256, 0, stream>>>(skew, negbuf);
  dtw_kernel<<<64, 64, 86272, stream>>>(skew, negbuf, out);
}

// Round 5
// 292.632 us; speedup vs baseline: 1.3813x; 1.1846x over previous
//
#include <hip/hip_runtime.h>
#include <hip/hip_bf16.h>
#include <stdint.h>

typedef __attribute__((ext_vector_type(8))) short short8v;     // 8 x bf16 (MFMA A/B frag)
typedef __attribute__((ext_vector_type(4))) float float4v;     // MFMA C/D frag / vec loads
typedef __attribute__((ext_vector_type(4))) unsigned short ushort4v;
typedef __attribute__((ext_vector_type(4))) unsigned int uint4v;

#define FINF __builtin_huge_valf()
#define BB 64
#define NN 512
#define DD 256
#define TT_SKEW 576   // skew rows: t = r + (j>>3) in [0, 511+63] -> pad to 576

// ws layout (bytes):
//   [0,        16777216)  xnb bf16 [B][N][D]
//   [16777216, 33554432)  ynb bf16 [B][N][D]
//   [33554432, 71303168)  cost_skew bf16 [B][576][512]  (cell (r,j) at row t=r+(j>>3), col j)
//   [71303168, 71303424)  negbuf f32 [64]

static __device__ __forceinline__ unsigned short f2bf(float f) {
  union { float f; uint32_t u; } a; a.f = f;
  uint32_t r = a.u + 0x7fffu + ((a.u >> 16) & 1u);   // RNE
  return (unsigned short)(r >> 16);
}
static __device__ __forceinline__ float bf2f(uint16_t v) {
  return __uint_as_float(((uint32_t)v) << 16);
}

// ---------------- Kernel 0: zero the skew-layout pad cells ----------------
// Row t<64: cols [8(t+1), 512) are pad; row t in [512,576): cols [0, 8(t-511)).
__global__ __launch_bounds__(64) void pad_zero_kernel(uint16_t* __restrict__ skew)
{
  const int bid = blockIdx.x;
  const int b = bid >> 7, k = bid & 127;
  const int t   = (k < 64) ? k : (448 + k);          // 0..63 or 512..575
  const int jlo = (k < 64) ? 8 * (t + 1) : 0;
  const int jhi = (k < 64) ? 512 : 8 * (t - 511);
  uint16_t* p = skew + ((size_t)b * TT_SKEW + t) * NN;
  const int j = jlo + (int)threadIdx.x * 8;
  if (j < jhi) *(uint4v*)(p + j) = (uint4v){0u, 0u, 0u, 0u};
}

// ---------------- Kernel 1: row-normalize + cast to bf16 ----------------
__global__ __launch_bounds__(256) void norm_cast_kernel(
    const float* __restrict__ x, const float* __restrict__ y,
    uint16_t* __restrict__ xnb, uint16_t* __restrict__ ynb)
{
  const int wave = threadIdx.x >> 6, lane = threadIdx.x & 63;
  const int row = blockIdx.x * 4 + wave;
  const float* src; uint16_t* dst;
  if (row < BB * NN) { src = x + (size_t)row * DD;            dst = xnb + (size_t)row * DD; }
  else               { src = y + (size_t)(row - BB*NN) * DD;  dst = ynb + (size_t)(row - BB*NN) * DD; }
  const float4v v = *(const float4v*)(src + lane * 4);
  float s = v[0]*v[0] + v[1]*v[1] + v[2]*v[2] + v[3]*v[3];
  #pragma unroll
  for (int d = 1; d < 64; d <<= 1) s += __shfl_xor(s, d, 64);
  const float inv = 1.0f / fmaxf(sqrtf(s), 1e-8f);
  ushort4v o;
  o[0] = f2bf(v[0] * inv); o[1] = f2bf(v[1] * inv);
  o[2] = f2bf(v[2] * inv); o[3] = f2bf(v[3] * inv);
  *(ushort4v*)(dst + lane * 4) = o;
}

// ---------------- Kernel 2: cost = 1 - xn·yn -> bf16 skewed layout ----------------
__global__ __launch_bounds__(256) void gemm_cost_kernel(
    const uint16_t* __restrict__ xnb, const uint16_t* __restrict__ ynb,
    uint16_t* __restrict__ skew)
{
  __shared__ uint16_t As[128 * 32];
  __shared__ uint16_t Bs[128 * 32];
  const int bid = blockIdx.x;
  const int b = bid >> 4, tm = (bid >> 2) & 3, tn = bid & 3;
  const int tid = threadIdx.x, wave = tid >> 6, lane = tid & 63;
  const int wr = wave >> 1, wc = wave & 1;

  const char* Ab = (const char*)(xnb + (size_t)b * NN * DD + (size_t)tm * 128 * DD);
  const char* Bb = (const char*)(ynb + (size_t)b * NN * DD + (size_t)tn * 128 * DD);

  float4v acc[4][4];
  #pragma unroll
  for (int i = 0; i < 4; i++)
    #pragma unroll
    for (int j = 0; j < 4; j++) acc[i][j] = (float4v){0.f, 0.f, 0.f, 0.f};

  const int seg0 = wave * 2;
  const int o0 = seg0 * 1024 + lane * 16;
  const int o1 = o0 + 1024;
  const int r0 = o0 >> 6, c0 = o0 & 63;
  const int r1 = o1 >> 6, c1 = o1 & 63;

  for (int kk = 0; kk < 8; kk++) {
    const int kb = kk * 64;
    __builtin_amdgcn_global_load_lds(
        (const __attribute__((address_space(1))) uint32_t*)(Ab + (size_t)r0 * 512 + kb + c0),
        (__attribute__((address_space(3))) uint32_t*)((char*)As + seg0 * 1024), 16, 0, 0);
    __builtin_amdgcn_global_load_lds(
        (const __attribute__((address_space(1))) uint32_t*)(Ab + (size_t)r1 * 512 + kb + c1),
        (__attribute__((address_space(3))) uint32_t*)((char*)As + (seg0 + 1) * 1024), 16, 0, 0);
    __builtin_amdgcn_global_load_lds(
        (const __attribute__((address_space(1))) uint32_t*)(Bb + (size_t)r0 * 512 + kb + c0),
        (__attribute__((address_space(3))) uint32_t*)((char*)Bs + seg0 * 1024), 16, 0, 0);
    __builtin_amdgcn_global_load_lds(
        (const __attribute__((address_space(1))) uint32_t*)(Bb + (size_t)r1 * 512 + kb + c1),
        (__attribute__((address_space(3))) uint32_t*)((char*)Bs + (seg0 + 1) * 1024), 16, 0, 0);
    __syncthreads();

    short8v af[4], bfr[4];
    #pragma unroll
    for (int mi = 0; mi < 4; mi++) {
      const int rr = wr * 64 + mi * 16 + (lane & 15);
      af[mi] = *(const short8v*)((const char*)As + rr * 64 + (lane >> 4) * 16);
    }
    #pragma unroll
    for (int nj = 0; nj < 4; nj++) {
      const int rr = wc * 64 + nj * 16 + (lane & 15);
      bfr[nj] = *(const short8v*)((const char*)Bs + rr * 64 + (lane >> 4) * 16);
    }
    #pragma unroll
    for (int mi = 0; mi < 4; mi++)
      #pragma unroll
      for (int nj = 0; nj < 4; nj++)
        acc[mi][nj] = __builtin_amdgcn_mfma_f32_16x16x32_bf16(af[mi], bfr[nj], acc[mi][nj], 0, 0, 0);
    __syncthreads();
  }

  uint16_t* Cb = skew + (size_t)b * TT_SKEW * NN;
  #pragma unroll
  for (int mi = 0; mi < 4; mi++)
    #pragma unroll
    for (int nj = 0; nj < 4; nj++) {
      const int cc = tn * 128 + wc * 64 + nj * 16 + (lane & 15);
      const int lg = cc >> 3;
      #pragma unroll
      for (int v = 0; v < 4; v++) {
        const int rr = tm * 128 + wr * 64 + mi * 16 + (lane >> 4) * 4 + v;
        Cb[(size_t)(rr + lg) * NN + cc] = f2bf(1.0f - acc[mi][nj][v]);
      }
    }
}

// ---------------- Kernel 3: neg[b] = LSE over column sums ----------------
__global__ __launch_bounds__(256) void neg_lse_kernel(
    const uint16_t* __restrict__ skew, float* __restrict__ negbuf)
{
  __shared__ float sm[8];
  const int b = blockIdx.x, tid = threadIdx.x;
  const int wave = tid >> 6, lane = tid & 63;
  const uint32_t* p = (const uint32_t*)(skew + (size_t)b * TT_SKEW * NN) + tid;
  float s0 = 0.f, s1 = 0.f;
  #pragma unroll 8
  for (int t = 0; t < TT_SKEW; ++t) {
    const uint32_t w = p[t * 256];
    s0 += __uint_as_float(w << 16);
    s1 += __uint_as_float(w & 0xFFFF0000u);
  }
  float m = fmaxf(s0, s1);
  #pragma unroll
  for (int d = 1; d < 64; d <<= 1) m = fmaxf(m, __shfl_xor(m, d, 64));
  if (lane == 0) sm[wave] = m;
  __syncthreads();
  m = fmaxf(fmaxf(sm[0], sm[1]), fmaxf(sm[2], sm[3]));
  float e = expf(s0 - m) + expf(s1 - m);
  #pragma unroll
  for (int d = 1; d < 64; d <<= 1) e += __shfl_xor(e, d, 64);
  if (lane == 0) sm[4 + wave] = e;
  __syncthreads();
  if (tid == 0) negbuf[b] = m + logf(sm[4] + sm[5] + sm[6] + sm[7]);
}

// ---------------- Kernel 4: DTW forward + backtrack + pos LSE ----------------
// One 64-lane wave per batch. Lane l owns cols [8l,8l+8); processes row r=tt-l.
// Cost rows live in an 8-deep REGISTER ring filled by asm global_load_dwordx4
// (compiler can't sink/spill/reorder it; vmcnt counts only these loads).
// Consume after s_waitcnt vmcnt(7) + sched_barrier(0); refill issued at end of
// body so the dead ring slot's registers are reused in place.
// LDS: dec u32[256][64] = 64KB | rlo | rhi | colpos | dump  (69760 B)
__global__ __launch_bounds__(64, 1) void dtw_kernel(
    const uint16_t* __restrict__ skew, const float* __restrict__ negbuf,
    float* __restrict__ out)
{
  extern __shared__ char lds_raw[];
  const int l = threadIdx.x;
  const int b = blockIdx.x;
  const uint16_t* csk = skew + (size_t)b * TT_SKEW * NN;
  const uint64_t base = (uint64_t)(uintptr_t)csk;     // uniform -> SGPR pair

  uint32_t voff = 16u * (uint32_t)l;                  // lane's 16B within a row
  const uint32_t voff_max = 16u * (uint32_t)l + 575u * 1024u;

  uint4v ring[8];
  #pragma unroll
  for (int i = 0; i < 8; ++i) {
    asm volatile("global_load_dwordx4 %0, %1, %2"
                 : "=v"(ring[i]) : "v"(voff), "s"(base) : "memory");
    voff += 1024u;
  }

  float tprev[8];
  #pragma unroll
  for (int c = 0; c < 8; ++c) tprev[c] = FINF;
  float sh_p_carry = FINF, cur_last = FINF;
  uint32_t rlane = (uint32_t)(0 - l);                 // r = tt - l (unsigned wrap)
  const uint32_t lane_dec = ((uint32_t)l) << 2;
  const uint32_t dump_addr = 69632u + (((uint32_t)l) << 1);

  for (int t = 0; t < TT_SKEW; t += 8) {
    #pragma unroll
    for (int u = 0; u < 8; ++u) {
      const int tt = t + u;
      asm volatile("s_waitcnt vmcnt(7)" ::: "memory");   // ring[u] (row tt) landed
      __builtin_amdgcn_sched_barrier(0);
      const uint4v cur = ring[u];

      float sh_c = __shfl_up(cur_last, 1, 64);   // tc[r][8l-1] from lane l-1
      float sh_p = sh_p_carry;                   // tc[r-1][8l-1]
      if (l == 0) { sh_p = FINF; sh_c = (tt == 0) ? 0.0f : FINF; }
      sh_p_carry = sh_c;
      const bool valid = (rlane < 512u);

      float S[8];
      {
        float c0 = __uint_as_float(cur[0] << 16);
        float c1 = __uint_as_float(cur[0] & 0xFFFF0000u);
        float c2 = __uint_as_float(cur[1] << 16);
        float c3 = __uint_as_float(cur[1] & 0xFFFF0000u);
        float c4 = __uint_as_float(cur[2] << 16);
        float c5 = __uint_as_float(cur[2] & 0xFFFF0000u);
        float c6 = __uint_as_float(cur[3] << 16);
        float c7 = __uint_as_float(cur[3] & 0xFFFF0000u);
        S[0] = c0; S[1] = S[0] + c1; S[2] = S[1] + c2; S[3] = S[2] + c3;
        S[4] = S[3] + c4; S[5] = S[4] + c5; S[6] = S[5] + c6; S[7] = S[6] + c7;
      }
      float dcp[8];
      dcp[0] = sh_p;
      #pragma unroll
      for (int c = 1; c < 8; ++c) dcp[c] = tprev[c - 1];
      float w8[8], PW[8];
      w8[0] = fminf(dcp[0], tprev[0]);
      #pragma unroll
      for (int c = 1; c < 8; ++c) w8[c] = fminf(dcp[c], tprev[c]) - S[c - 1];
      PW[0] = w8[0];
      #pragma unroll
      for (int c = 1; c < 8; ++c) PW[c] = fminf(PW[c - 1], w8[c]);
      float tnv[8];
      #pragma unroll
      for (int c = 0; c < 8; ++c) tnv[c] = fminf(PW[c], sh_c) + S[c];
      float lc[8];
      lc[0] = sh_c;
      #pragma unroll
      for (int c = 1; c < 8; ++c) lc[c] = tnv[c - 1];
      uint32_t word = 0;
      #pragma unroll
      for (int c = 0; c < 8; ++c) {
        // tie-break diag > up > left (reference equality-chain order)
        const bool diag = dcp[c] <= fminf(tprev[c], lc[c]);
        const uint32_t dd = diag ? 0u : ((tprev[c] <= lc[c]) ? 1u : 2u);
        word |= dd << (2 * c);
      }
      // dec u16 at byte (r>>1)*256 + l*4 + (r&1)*2  (4B lane stride: 2-way, free)
      const uint32_t wbyte = ((rlane & ~1u) << 7) | ((rlane & 1u) << 1) | lane_dec;
      const uint32_t waddr = valid ? wbyte : dump_addr;
      *(uint16_t*)(lds_raw + waddr) = (uint16_t)word;
      #pragma unroll
      for (int c = 0; c < 8; ++c) tprev[c] = valid ? tnv[c] : tprev[c];
      cur_last = tprev[7];
      rlane += 1u;

      // refill: row tt+8 into the (now dead) slot; clamp keeps vmcnt count uniform
      asm volatile("global_load_dwordx4 %0, %1, %2"
                   : "=v"(ring[u]) : "v"(voff), "s"(base) : "memory");
      voff += 1024u;
      if (voff > voff_max) voff = voff_max;
    }
  }
  // drain: late loads land in registers the epilogue will reuse
  asm volatile("s_waitcnt vmcnt(0)" ::: "memory");
  __builtin_amdgcn_sched_barrier(0);

  uint16_t* rlo    = (uint16_t*)(lds_raw + 65536);
  uint16_t* rhi    = (uint16_t*)(lds_raw + 66560);
  float*    colpos = (float*)  (lds_raw + 67584);
  const uint32_t* dec32 = (const uint32_t*)lds_raw;

  // ---- backtrack: per-row contiguous column interval of the path ----
  for (int r = l; r < NN; r += 64) { rlo[r] = 1; rhi[r] = 0; colpos[r] = 0.0f; }
  __syncthreads();
  if (l == 0) {
    int i = NN - 1, j = NN - 1, hicur = NN - 1;
    int cidx = -1; uint32_t cw = 0;
    while (i > 0 && j > 0) {
      const int widx = (i >> 1) * 64 + (j >> 3);
      if (widx != cidx) { cw = dec32[widx]; cidx = widx; }
      const uint32_t dd = (cw >> (((i & 1) << 4) + ((j & 7) << 1))) & 3u;
      if (dd == 2u) { j--; }           // left: stay in row
      else {
        rlo[i] = (uint16_t)j; rhi[i] = (uint16_t)hicur;  // leave row i
        i--;
        if (dd == 0u) j--;             // diag also moves left
        hicur = j;                     // entry column of new row
      }
    }
    rlo[i] = (uint16_t)j; rhi[i] = (uint16_t)hicur;      // pending row at exit
  }
  __syncthreads();
  // colpos[m] = sum_n cost*path (rows parallel across lanes; skew-layout reads)
  for (int r = l; r < NN; r += 64) {
    const int lo = rlo[r], hi = rhi[r];
    for (int j = lo; j <= hi; j++) {
      const float cv = bf2f(csk[(size_t)(r + (j >> 3)) * NN + j]);
      atomicAdd(&colpos[j], cv);
    }
  }
  // reference always sets p[0,0]=1
  if (l == 0 && rlo[0] != 0) atomicAdd(&colpos[0], bf2f(csk[0]));
  __syncthreads();

  // ---- pos = logsumexp over colpos ----
  float mv[8];
  float mx2 = -FINF;
  #pragma unroll
  for (int k = 0; k < 8; k++) { mv[k] = colpos[l + 64 * k]; mx2 = fmaxf(mx2, mv[k]); }
  #pragma unroll
  for (int d = 1; d < 64; d <<= 1) mx2 = fmaxf(mx2, __shfl_xor(mx2, d, 64));
  float se2 = 0.f;
  #pragma unroll
  for (int k = 0; k < 8; k++) se2 += expf(mv[k] - mx2);
  #pragma unroll
  for (int d = 1; d < 64; d <<= 1) se2 += __shfl_xor(se2, d, 64);
  const float pos = mx2 + logf(se2);

  if (l == 0) out[b] = pos - negbuf[b];
}

extern "C" void kernel_launch(void* const* d_in, const int* in_sizes, int n_in,
                              void* d_out, int out_size, void* d_ws, size_t ws_size,
                              hipStream_t stream)
{
  (void)in_sizes; (void)n_in; (void)out_size; (void)ws_size;
  const float* x = (const float*)d_in[0];
  const float* y = (const float*)d_in[1];
  float* out = (float*)d_out;
  char* ws = (char*)d_ws;
  uint16_t* xnb  = (uint16_t*)ws;
  uint16_t* ynb  = (uint16_t*)(ws + (size_t)16777216);
  uint16_t* skew = (uint16_t*)(ws + (size_t)33554432);
  float*  negbuf = (float*)  (ws + (size_t)71303168);

  (void)hipFuncSetAttribute((const void*)dtw_kernel,
                            hipFuncAttributeMaxDynamicSharedMemorySize, 69888);

  pad_zero_kernel<<<8192, 64, 0, stream>>>(skew);
  norm_cast_kernel<<<16384, 256, 0, stream>>>(x, y, xnb, ynb);
  gemm_cost_kernel<<<1024, 256, 0, stream>>>(xnb, ynb, skew);
  neg_lse_kernel<<<64, 256, 0, stream>>>(skew, negbuf);
  dtw_kernel<<<64, 64, 69888, stream>>>(skew, negbuf, out);
}

// Round 6
// 289.708 us; speedup vs baseline: 1.3953x; 1.0101x over previous
//
#include <hip/hip_runtime.h>
#include <hip/hip_bf16.h>
#include <stdint.h>

typedef __attribute__((ext_vector_type(8))) short short8v;     // 8 x bf16 (MFMA A/B frag)
typedef __attribute__((ext_vector_type(4))) float float4v;     // MFMA C/D frag / vec loads
typedef __attribute__((ext_vector_type(4))) unsigned short ushort4v;
typedef __attribute__((ext_vector_type(4))) unsigned int uint4v;

#define FINF __builtin_huge_valf()
#define BB 64
#define NN 512
#define DD 256
#define TT_SKEW 576   // skew rows: t = r + (j>>3) in [0, 511+63] -> pad to 576

// ws layout (bytes):
//   [0,        16777216)  xnb bf16 [B][N][D]
//   [16777216, 33554432)  ynb bf16 [B][N][D]
//   [33554432, 71303168)  cost_skew bf16 [B][576][512]  (cell (r,j) at row t=r+(j>>3), col j)
//   [71303168, 71303424)  negbuf f32 [64]

static __device__ __forceinline__ unsigned short f2bf(float f) {
  union { float f; uint32_t u; } a; a.f = f;
  uint32_t r = a.u + 0x7fffu + ((a.u >> 16) & 1u);   // RNE
  return (unsigned short)(r >> 16);
}
static __device__ __forceinline__ float bf2f(uint16_t v) {
  return __uint_as_float(((uint32_t)v) << 16);
}

// ---------------- Kernel 0: zero the skew-layout pad cells ----------------
// Row t<64: cols [8(t+1), 512) are pad; row t in [512,576): cols [0, 8(t-511)).
__global__ __launch_bounds__(64) void pad_zero_kernel(uint16_t* __restrict__ skew)
{
  const int bid = blockIdx.x;
  const int b = bid >> 7, k = bid & 127;
  const int t   = (k < 64) ? k : (448 + k);          // 0..63 or 512..575
  const int jlo = (k < 64) ? 8 * (t + 1) : 0;
  const int jhi = (k < 64) ? 512 : 8 * (t - 511);
  uint16_t* p = skew + ((size_t)b * TT_SKEW + t) * NN;
  const int j = jlo + (int)threadIdx.x * 8;
  if (j < jhi) *(uint4v*)(p + j) = (uint4v){0u, 0u, 0u, 0u};
}

// ---------------- Kernel 1: row-normalize + cast to bf16 ----------------
__global__ __launch_bounds__(256) void norm_cast_kernel(
    const float* __restrict__ x, const float* __restrict__ y,
    uint16_t* __restrict__ xnb, uint16_t* __restrict__ ynb)
{
  const int wave = threadIdx.x >> 6, lane = threadIdx.x & 63;
  const int row = blockIdx.x * 4 + wave;
  const float* src; uint16_t* dst;
  if (row < BB * NN) { src = x + (size_t)row * DD;            dst = xnb + (size_t)row * DD; }
  else               { src = y + (size_t)(row - BB*NN) * DD;  dst = ynb + (size_t)(row - BB*NN) * DD; }
  const float4v v = *(const float4v*)(src + lane * 4);
  float s = v[0]*v[0] + v[1]*v[1] + v[2]*v[2] + v[3]*v[3];
  #pragma unroll
  for (int d = 1; d < 64; d <<= 1) s += __shfl_xor(s, d, 64);
  const float inv = 1.0f / fmaxf(sqrtf(s), 1e-8f);
  ushort4v o;
  o[0] = f2bf(v[0] * inv); o[1] = f2bf(v[1] * inv);
  o[2] = f2bf(v[2] * inv); o[3] = f2bf(v[3] * inv);
  *(ushort4v*)(dst + lane * 4) = o;
}

// ---------------- Kernel 2: cost = 1 - xn·yn -> bf16 skewed layout ----------------
__global__ __launch_bounds__(256) void gemm_cost_kernel(
    const uint16_t* __restrict__ xnb, const uint16_t* __restrict__ ynb,
    uint16_t* __restrict__ skew)
{
  __shared__ uint16_t As[128 * 32];
  __shared__ uint16_t Bs[128 * 32];
  const int bid = blockIdx.x;
  const int b = bid >> 4, tm = (bid >> 2) & 3, tn = bid & 3;
  const int tid = threadIdx.x, wave = tid >> 6, lane = tid & 63;
  const int wr = wave >> 1, wc = wave & 1;

  const char* Ab = (const char*)(xnb + (size_t)b * NN * DD + (size_t)tm * 128 * DD);
  const char* Bb = (const char*)(ynb + (size_t)b * NN * DD + (size_t)tn * 128 * DD);

  float4v acc[4][4];
  #pragma unroll
  for (int i = 0; i < 4; i++)
    #pragma unroll
    for (int j = 0; j < 4; j++) acc[i][j] = (float4v){0.f, 0.f, 0.f, 0.f};

  const int seg0 = wave * 2;
  const int o0 = seg0 * 1024 + lane * 16;
  const int o1 = o0 + 1024;
  const int r0 = o0 >> 6, c0 = o0 & 63;
  const int r1 = o1 >> 6, c1 = o1 & 63;

  for (int kk = 0; kk < 8; kk++) {
    const int kb = kk * 64;
    __builtin_amdgcn_global_load_lds(
        (const __attribute__((address_space(1))) uint32_t*)(Ab + (size_t)r0 * 512 + kb + c0),
        (__attribute__((address_space(3))) uint32_t*)((char*)As + seg0 * 1024), 16, 0, 0);
    __builtin_amdgcn_global_load_lds(
        (const __attribute__((address_space(1))) uint32_t*)(Ab + (size_t)r1 * 512 + kb + c1),
        (__attribute__((address_space(3))) uint32_t*)((char*)As + (seg0 + 1) * 1024), 16, 0, 0);
    __builtin_amdgcn_global_load_lds(
        (const __attribute__((address_space(1))) uint32_t*)(Bb + (size_t)r0 * 512 + kb + c0),
        (__attribute__((address_space(3))) uint32_t*)((char*)Bs + seg0 * 1024), 16, 0, 0);
    __builtin_amdgcn_global_load_lds(
        (const __attribute__((address_space(1))) uint32_t*)(Bb + (size_t)r1 * 512 + kb + c1),
        (__attribute__((address_space(3))) uint32_t*)((char*)Bs + (seg0 + 1) * 1024), 16, 0, 0);
    __syncthreads();

    short8v af[4], bfr[4];
    #pragma unroll
    for (int mi = 0; mi < 4; mi++) {
      const int rr = wr * 64 + mi * 16 + (lane & 15);
      af[mi] = *(const short8v*)((const char*)As + rr * 64 + (lane >> 4) * 16);
    }
    #pragma unroll
    for (int nj = 0; nj < 4; nj++) {
      const int rr = wc * 64 + nj * 16 + (lane & 15);
      bfr[nj] = *(const short8v*)((const char*)Bs + rr * 64 + (lane >> 4) * 16);
    }
    #pragma unroll
    for (int mi = 0; mi < 4; mi++)
      #pragma unroll
      for (int nj = 0; nj < 4; nj++)
        acc[mi][nj] = __builtin_amdgcn_mfma_f32_16x16x32_bf16(af[mi], bfr[nj], acc[mi][nj], 0, 0, 0);
    __syncthreads();
  }

  uint16_t* Cb = skew + (size_t)b * TT_SKEW * NN;
  #pragma unroll
  for (int mi = 0; mi < 4; mi++)
    #pragma unroll
    for (int nj = 0; nj < 4; nj++) {
      const int cc = tn * 128 + wc * 64 + nj * 16 + (lane & 15);
      const int lg = cc >> 3;
      #pragma unroll
      for (int v = 0; v < 4; v++) {
        const int rr = tm * 128 + wr * 64 + mi * 16 + (lane >> 4) * 4 + v;
        Cb[(size_t)(rr + lg) * NN + cc] = f2bf(1.0f - acc[mi][nj][v]);
      }
    }
}

// ---------------- Kernel 3: neg[b] = LSE over column sums ----------------
__global__ __launch_bounds__(256) void neg_lse_kernel(
    const uint16_t* __restrict__ skew, float* __restrict__ negbuf)
{
  __shared__ float sm[8];
  const int b = blockIdx.x, tid = threadIdx.x;
  const int wave = tid >> 6, lane = tid & 63;
  const uint32_t* p = (const uint32_t*)(skew + (size_t)b * TT_SKEW * NN) + tid;
  float s0 = 0.f, s1 = 0.f;
  #pragma unroll 8
  for (int t = 0; t < TT_SKEW; ++t) {
    const uint32_t w = p[t * 256];
    s0 += __uint_as_float(w << 16);
    s1 += __uint_as_float(w & 0xFFFF0000u);
  }
  float m = fmaxf(s0, s1);
  #pragma unroll
  for (int d = 1; d < 64; d <<= 1) m = fmaxf(m, __shfl_xor(m, d, 64));
  if (lane == 0) sm[wave] = m;
  __syncthreads();
  m = fmaxf(fmaxf(sm[0], sm[1]), fmaxf(sm[2], sm[3]));
  float e = expf(s0 - m) + expf(s1 - m);
  #pragma unroll
  for (int d = 1; d < 64; d <<= 1) e += __shfl_xor(e, d, 64);
  if (lane == 0) sm[4 + wave] = e;
  __syncthreads();
  if (tid == 0) negbuf[b] = m + logf(sm[4] + sm[5] + sm[6] + sm[7]);
}

// ---------------- Kernel 4: DTW forward + backtrack + pos LSE ----------------
// One 64-lane wave per batch. Lane l owns cols [8l,8l+8); processes row r=tt-l.
// 8-deep register ring via asm global_load_dwordx4; waits are DATAFLOW-TIED
// ("+v"(ring[u]) on the s_waitcnt) so only ring consumption is ordered — the
// shfl/VALU/LDS stream schedules freely across steps. Shuffle is issued at the
// END of a step (sh_c_next) so its DS latency hides under the step's tail.
// tn7 computed via min-TREE (critical path: cndmask+shfl+fmin+add).
// LDS: dec u32[256][64] = 64KB | rlo | rhi | colpos | dump  (69888 B)
__global__ __launch_bounds__(64, 1) void dtw_kernel(
    const uint16_t* __restrict__ skew, const float* __restrict__ negbuf,
    float* __restrict__ out)
{
  extern __shared__ char lds_raw[];
  const int l = threadIdx.x;
  const int b = blockIdx.x;
  const uint16_t* csk = skew + (size_t)b * TT_SKEW * NN;
  const uint64_t base = (uint64_t)(uintptr_t)csk;     // uniform -> SGPR pair

  uint32_t voff = 16u * (uint32_t)l;                  // lane's 16B within a row
  uint4v ring[8];
  #pragma unroll
  for (int i = 0; i < 8; ++i) {
    asm volatile("global_load_dwordx4 %0, %1, %2"
                 : "=v"(ring[i]) : "v"(voff), "s"(base));
    voff += 1024u;
  }

  float tprev[8];
  #pragma unroll
  for (int c = 0; c < 8; ++c) tprev[c] = FINF;
  float cur_last = FINF, sh_p_carry = FINF, sh_c_next = FINF;
  uint32_t rlane = (uint32_t)(0 - l);                 // r = tt - l (unsigned wrap)
  const uint32_t lane_dec = ((uint32_t)l) << 2;
  const uint32_t dump_addr = 69632u + (((uint32_t)l) << 1);
  const bool is0 = (l == 0);

  auto STEP = [&](int tt, uint4v cur) {
    float sh_c = sh_c_next, sh_p = sh_p_carry;
    if (is0) { sh_p = FINF; sh_c = (tt == 0) ? 0.0f : FINF; }
    sh_p_carry = sh_c;
    const bool valid = (rlane < 512u);

    // unpack bf16 costs + prefix sums
    const float c0 = __uint_as_float(cur[0] << 16);
    const float c1 = __uint_as_float(cur[0] & 0xFFFF0000u);
    const float c2 = __uint_as_float(cur[1] << 16);
    const float c3 = __uint_as_float(cur[1] & 0xFFFF0000u);
    const float c4 = __uint_as_float(cur[2] << 16);
    const float c5 = __uint_as_float(cur[2] & 0xFFFF0000u);
    const float c6 = __uint_as_float(cur[3] << 16);
    const float c7 = __uint_as_float(cur[3] & 0xFFFF0000u);
    float S[8];
    S[0] = c0; S[1] = S[0] + c1; S[2] = S[1] + c2; S[3] = S[2] + c3;
    S[4] = S[3] + c4; S[5] = S[4] + c5; S[6] = S[5] + c6; S[7] = S[6] + c7;

    float dcp[8];
    dcp[0] = sh_p;
    #pragma unroll
    for (int c = 1; c < 8; ++c) dcp[c] = tprev[c - 1];
    float mu[8], w8[8];
    #pragma unroll
    for (int c = 0; c < 8; ++c) mu[c] = fminf(dcp[c], tprev[c]);
    w8[0] = mu[0];
    #pragma unroll
    for (int c = 1; c < 8; ++c) w8[c] = mu[c] - S[c - 1];

    // PW7 via tree: shortest path to cur_last -> shfl
    const float m01 = fminf(w8[0], w8[1]), m23 = fminf(w8[2], w8[3]);
    const float m45 = fminf(w8[4], w8[5]), m67 = fminf(w8[6], w8[7]);
    const float PW7 = fminf(fminf(m01, m23), fminf(m45, m67));
    const float tn7 = fminf(PW7, sh_c) + S[7];
    const float old7 = tprev[7];
    cur_last = valid ? tn7 : old7;
    sh_c_next = __shfl_up(cur_last, 1, 64);   // latency hidden by tail below

    // remaining prefix (off critical path)
    float PW[8];
    PW[0] = w8[0];
    #pragma unroll
    for (int c = 1; c < 7; ++c) PW[c] = fminf(PW[c - 1], w8[c]);
    PW[7] = PW7;
    float tnv[8];
    #pragma unroll
    for (int c = 0; c < 8; ++c) tnv[c] = fminf(PW[c], sh_c) + S[c];
    float lc[8];
    lc[0] = sh_c;
    #pragma unroll
    for (int c = 1; c < 8; ++c) lc[c] = tnv[c - 1];

    // decisions: dd = (lc < min(dcp,up)) ? 2 : (up < dcp ? 1 : 0)
    // == reference tie-break chain diag(<=) > up(<=) > left
    uint32_t word = 0;
    #pragma unroll
    for (int c = 0; c < 8; ++c) {
      const uint32_t t01 = (tprev[c] < dcp[c]) ? 1u : 0u;
      const uint32_t dd = (lc[c] < mu[c]) ? 2u : t01;
      word |= dd << (2 * c);
    }
    const uint32_t wbyte = ((rlane & ~1u) << 7) | ((rlane & 1u) << 1) | lane_dec;
    *(uint16_t*)(lds_raw + (valid ? wbyte : dump_addr)) = (uint16_t)word;
    #pragma unroll
    for (int c = 0; c < 8; ++c) tprev[c] = valid ? tnv[c] : tprev[c];
    rlane += 1u;
  };

  // main: steps 0..567, each refills row tt+8 (rows 8..575 exactly)
  for (int t = 0; t < 568; t += 8) {
    #pragma unroll
    for (int u = 0; u < 8; ++u) {
      const int tt = t + u;
      asm volatile("s_waitcnt vmcnt(7)" : "+v"(ring[u]));
      const uint4v cur = ring[u];
      STEP(tt, cur);
      asm volatile("global_load_dwordx4 %0, %1, %2"
                   : "=v"(ring[u]) : "v"(voff), "s"(base));
      voff += 1024u;
    }
  }
  // tail: steps 568..575, no refills (waits pass instantly)
  #pragma unroll
  for (int u = 0; u < 8; ++u) {
    asm volatile("s_waitcnt vmcnt(7)" : "+v"(ring[u]));
    STEP(568 + u, ring[u]);
  }
  asm volatile("s_waitcnt vmcnt(0)" ::: "memory");

  uint16_t* rlo    = (uint16_t*)(lds_raw + 65536);
  uint16_t* rhi    = (uint16_t*)(lds_raw + 66560);
  float*    colpos = (float*)  (lds_raw + 67584);
  const uint32_t* dec32 = (const uint32_t*)lds_raw;

  // ---- backtrack: per-row contiguous column interval of the path ----
  for (int r = l; r < NN; r += 64) { rlo[r] = 1; rhi[r] = 0; colpos[r] = 0.0f; }
  __syncthreads();
  if (l == 0) {
    int i = NN - 1, j = NN - 1, hicur = NN - 1;
    int cidx = -1; uint32_t cw = 0;
    while (i > 0 && j > 0) {
      const int widx = (i >> 1) * 64 + (j >> 3);
      if (widx != cidx) { cw = dec32[widx]; cidx = widx; }
      const uint32_t dd = (cw >> (((i & 1) << 4) + ((j & 7) << 1))) & 3u;
      if (dd == 2u) { j--; }           // left: stay in row
      else {
        rlo[i] = (uint16_t)j; rhi[i] = (uint16_t)hicur;  // leave row i
        i--;
        if (dd == 0u) j--;             // diag also moves left
        hicur = j;                     // entry column of new row
      }
    }
    rlo[i] = (uint16_t)j; rhi[i] = (uint16_t)hicur;      // pending row at exit
  }
  __syncthreads();
  // colpos[m] = sum_n cost*path (rows parallel across lanes; skew-layout reads)
  for (int r = l; r < NN; r += 64) {
    const int lo = rlo[r], hi = rhi[r];
    for (int j = lo; j <= hi; j++) {
      const float cv = bf2f(csk[(size_t)(r + (j >> 3)) * NN + j]);
      atomicAdd(&colpos[j], cv);
    }
  }
  // reference always sets p[0,0]=1
  if (l == 0 && rlo[0] != 0) atomicAdd(&colpos[0], bf2f(csk[0]));
  __syncthreads();

  // ---- pos = logsumexp over colpos ----
  float mv[8];
  float mx2 = -FINF;
  #pragma unroll
  for (int k = 0; k < 8; k++) { mv[k] = colpos[l + 64 * k]; mx2 = fmaxf(mx2, mv[k]); }
  #pragma unroll
  for (int d = 1; d < 64; d <<= 1) mx2 = fmaxf(mx2, __shfl_xor(mx2, d, 64));
  float se2 = 0.f;
  #pragma unroll
  for (int k = 0; k < 8; k++) se2 += expf(mv[k] - mx2);
  #pragma unroll
  for (int d = 1; d < 64; d <<= 1) se2 += __shfl_xor(se2, d, 64);
  const float pos = mx2 + logf(se2);

  if (l == 0) out[b] = pos - negbuf[b];
}

extern "C" void kernel_launch(void* const* d_in, const int* in_sizes, int n_in,
                              void* d_out, int out_size, void* d_ws, size_t ws_size,
                              hipStream_t stream)
{
  (void)in_sizes; (void)n_in; (void)out_size; (void)ws_size;
  const float* x = (const float*)d_in[0];
  const float* y = (const float*)d_in[1];
  float* out = (float*)d_out;
  char* ws = (char*)d_ws;
  uint16_t* xnb  = (uint16_t*)ws;
  uint16_t* ynb  = (uint16_t*)(ws + (size_t)16777216);
  uint16_t* skew = (uint16_t*)(ws + (size_t)33554432);
  float*  negbuf = (float*)  (ws + (size_t)71303168);

  (void)hipFuncSetAttribute((const void*)dtw_kernel,
                            hipFuncAttributeMaxDynamicSharedMemorySize, 69888);

  pad_zero_kernel<<<8192, 64, 0, stream>>>(skew);
  norm_cast_kernel<<<16384, 256, 0, stream>>>(x, y, xnb, ynb);
  gemm_cost_kernel<<<1024, 256, 0, stream>>>(xnb, ynb, skew);
  neg_lse_kernel<<<64, 256, 0, stream>>>(skew, negbuf);
  dtw_kernel<<<64, 64, 69888, stream>>>(skew, negbuf, out);
}